// Round 18
// baseline (284.672 us; speedup 1.0000x reference)
//
#include <hip/hip_runtime.h>
#include <stdint.h>

// B=4, T=2048, C=1024, H=16, D=64.
// Inputs/outputs FP32 (per reference). Internal: bf16 MFMA, fp32 accum.

using u16 = unsigned short;
using u32 = unsigned int;
typedef __attribute__((ext_vector_type(8)))  __bf16 bf16x8;
typedef __attribute__((ext_vector_type(4)))  float  floatx4;
typedef __attribute__((ext_vector_type(16))) float  f32x16;
typedef __attribute__((ext_vector_type(2)))  unsigned int u32x2;

#define QSCALE 0.18033688011112043f   // 0.125 * log2(e), folded into Q projection

__device__ __forceinline__ u16 f2b(float f) {
    union { float f; u32 i; } x; x.f = f;
    return (u16)((x.i + 0x7fffu + ((x.i >> 16) & 1u)) >> 16);
}
__device__ __forceinline__ u32 fbits(float f) { union { float f; u32 i; } x; x.f = f; return x.i; }
// pack two fp32 -> (bf16(b)<<16)|bf16(a) : 2 adds + 1 v_perm
__device__ __forceinline__ u32 pkbf(float a, float b) {
    u32 ia = fbits(a) + 0x8000u, ib = fbits(b) + 0x8000u;
    return __builtin_amdgcn_perm(ib, ia, 0x07060302u);
}
// single-instruction RNE pack: D.lo=bf16(a), D.hi=bf16(b)
__device__ __forceinline__ u32 cvtpk(float a, float b) {
    u32 r; asm("v_cvt_pk_bf16_f32 %0, %1, %2" : "=v"(r) : "v"(a), "v"(b)); return r;
}
__device__ __forceinline__ bf16x8 ld16B(const u16* p) {
    bf16x8 v; __builtin_memcpy(&v, p, 16); return v;
}
__device__ __forceinline__ void async16(const u16* g, u16* l) {
    __builtin_amdgcn_global_load_lds((const __attribute__((address_space(1))) unsigned int*)g,
                                     (__attribute__((address_space(3))) unsigned int*)l,
                                     16, 0, 0);
}

// ---------------- convert fp32 -> bf16 (x + 4 weight matrices) ----------------
__global__ __launch_bounds__(256) void convert_kernel(
    const float* __restrict__ x,
    const float* __restrict__ Wq, const float* __restrict__ Wk,
    const float* __restrict__ Wv, const float* __restrict__ Wo,
    u16* __restrict__ xb, u16* __restrict__ wqb, u16* __restrict__ wkb,
    u16* __restrict__ wvb, u16* __restrict__ wob)
{
    size_t e = ((size_t)blockIdx.x * 256 + threadIdx.x) * 4;
    const float* src; u16* dst; size_t off;
    const size_t XN = (size_t)8 << 20;
    if (e < XN) { src = x; dst = xb; off = e; }
    else {
        size_t k = e - XN;
        int w = (int)(k >> 20);
        off = k & ((1u << 20) - 1);
        src = (w == 0) ? Wq : (w == 1) ? Wk : (w == 2) ? Wv : Wo;
        dst = (w == 0) ? wqb : (w == 1) ? wkb : (w == 2) ? wvb : wob;
    }
    float4 f = *(const float4*)(src + off);
    u32 dws[2] = { pkbf(f.x, f.y), pkbf(f.z, f.w) };
    __builtin_memcpy(dst + off, dws, 8);
}

// ---------------- shared GEMM K-loop: single-buffer 32KB (m97 form), occupancy-first ----------
// acc = A[128 rows m0..] . W[128 rows n0..]^T, K=1024, BK=64, XOR-swizzled LDS.
__device__ __forceinline__ void gemm_loop(const u16* __restrict__ A, const u16* __restrict__ W,
                                          int m0, int n0, floatx4 (&acc)[4][4],
                                          u16* __restrict__ sA, u16* __restrict__ sB)
{
    constexpr int K = 1024;
    const int tid  = threadIdx.x;
    const int wave = tid >> 6, lane = tid & 63;
    const int wr = wave >> 1, wc = wave & 1;
    const int quad = lane >> 4, l15 = lane & 15;

    #pragma unroll
    for (int i = 0; i < 4; ++i)
        #pragma unroll
        for (int j = 0; j < 4; ++j)
            acc[i][j] = (floatx4){0.f, 0.f, 0.f, 0.f};

    const int rstage = lane >> 3;              // 8 rows per async16
    const int gstage = lane & 7;

    #pragma unroll 1
    for (int kb = 0; kb < 16; ++kb) {
        __syncthreads();                       // previous tile fully consumed
        const int k0 = kb * 64;
        #pragma unroll
        for (int j = 0; j < 4; ++j) {
            int r  = wave * 32 + j * 8 + rstage;
            int kg = gstage ^ (r & 7);
            async16(A + (size_t)(m0 + r) * K + k0 + kg * 8, &sA[(wave * 32 + j * 8) * 64]);
            async16(W + (size_t)(n0 + r) * K + k0 + kg * 8, &sB[(wave * 32 + j * 8) * 64]);
        }
        __syncthreads();                       // drains vmcnt (global_load_lds)

        #pragma unroll
        for (int kk = 0; kk < 2; ++kk) {
            bf16x8 af[4], bf[4];
            const int kg = kk * 4 + quad;
            #pragma unroll
            for (int t = 0; t < 4; ++t) {
                int ra = wr * 64 + t * 16 + l15;
                af[t] = ld16B(&sA[ra * 64 + ((kg ^ (ra & 7)) * 8)]);
                int rb = wc * 64 + t * 16 + l15;
                bf[t] = ld16B(&sB[rb * 64 + ((kg ^ (rb & 7)) * 8)]);
            }
            #pragma unroll
            for (int mt = 0; mt < 4; ++mt)
                #pragma unroll
                for (int nt = 0; nt < 4; ++nt)
                    acc[mt][nt] = __builtin_amdgcn_mfma_f32_16x16x32_bf16(af[mt], bf[nt], acc[mt][nt], 0, 0, 0);
        }
    }
}

// ---------------- fused QKV projection ----------------
// Wcat = [3072,1024]. 1-D grid 1536; XCD-partitioned swizzle: each XCD owns 8 m-tiles
// (x slice 2 MB -> L2-resident), n varies per slot.
// z=0: Q row-major * QSCALE; z=1: K row-major; z=2: Vt [bh*64+d][2048].
__global__ __launch_bounds__(256, 3) void qkv_kernel(
    const u16* __restrict__ x, const u16* __restrict__ Wcat,
    const float* __restrict__ bq, const float* __restrict__ bk, const float* __restrict__ bv,
    u16* __restrict__ q, u16* __restrict__ k, u16* __restrict__ vt)
{
    __shared__ __align__(16) u16 sA[128 * 64];
    __shared__ __align__(16) u16 sB[128 * 64];
    const int id = blockIdx.x;
    const int xcd = id & 7, slot = id >> 3;        // 192 slots per XCD
    const int m0 = (xcd * 8 + (slot & 7)) * 128;   // m-tile 0..63
    const int n0 = (slot >> 3) * 128;              // n-tile 0..23
    floatx4 acc[4][4];
    gemm_loop(x, Wcat, m0, n0, acc, sA, sB);

    const int tid = threadIdx.x;
    const int wave = tid >> 6, lane = tid & 63;
    const int wr = wave >> 1, wc = wave & 1;
    const int quad = lane >> 4, l15 = lane & 15;

    const int z = n0 >> 10;
    const float* bb = (z == 0) ? bq : (z == 1) ? bk : bv;
    const float scale = (z == 0) ? QSCALE : 1.0f;
    u16* o = (z == 0) ? q : k;

    #pragma unroll
    for (int nt = 0; nt < 4; ++nt) {
        int col  = n0 + wc * 64 + nt * 16 + l15;   // in [0,3072)
        int c    = col & 1023;
        float bv_ = bb[c];
        #pragma unroll
        for (int mt = 0; mt < 4; ++mt) {
            int row0 = m0 + wr * 64 + mt * 16 + quad * 4;
            if (z == 2) {
                // Vt: addr = ((b*16+h)*64+d)*2048 + t, t=row contiguous -> 8B store
                float v0 = acc[mt][nt][0] + bv_, v1 = acc[mt][nt][1] + bv_;
                float v2 = acc[mt][nt][2] + bv_, v3 = acc[mt][nt][3] + bv_;
                u32 dws[2] = { pkbf(v0, v1), pkbf(v2, v3) };
                int b = row0 >> 11, t0 = row0 & 2047;
                size_t idx = ((size_t)((b * 16 + (c >> 6)) * 64 + (c & 63)) * 2048) + t0;
                __builtin_memcpy(vt + idx, dws, 8);
            } else {
                #pragma unroll
                for (int r = 0; r < 4; ++r) {
                    float v = (acc[mt][nt][r] + bv_) * scale;
                    o[(size_t)(row0 + r) * 1024 + c] = f2b(v);
                }
            }
        }
    }
}

// ---------------- output projection ----------------
__global__ __launch_bounds__(256, 3) void proj_kernel(
    const u16* __restrict__ y, const u16* __restrict__ Wo, const float* __restrict__ bo,
    float* __restrict__ out)
{
    __shared__ __align__(16) u16 sA[128 * 64];
    __shared__ __align__(16) u16 sB[128 * 64];
    const int id = blockIdx.x;
    const int xcd = id & 7, slot = id >> 3;        // 64 slots per XCD
    const int m0 = (xcd * 8 + (slot & 7)) * 128;   // m-tile 0..63
    const int n0 = (slot >> 3) * 128;              // n-tile 0..7
    floatx4 acc[4][4];
    gemm_loop(y, Wo, m0, n0, acc, sA, sB);

    const int tid = threadIdx.x;
    const int wave = tid >> 6, lane = tid & 63;
    const int wr = wave >> 1, wc = wave & 1;
    const int quad = lane >> 4, l15 = lane & 15;

    #pragma unroll
    for (int nt = 0; nt < 4; ++nt) {
        int col = n0 + wc * 64 + nt * 16 + l15;
        float bv_ = bo[col];
        #pragma unroll
        for (int mt = 0; mt < 4; ++mt) {
            int row0 = m0 + wr * 64 + mt * 16 + quad * 4;
            #pragma unroll
            for (int r = 0; r < 4; ++r)
                out[(size_t)(row0 + r) * 1024 + col] = acc[mt][nt][r] + bv_;
        }
    }
}

// ---------------- Flash attention: cross-kt pipeline, S-FIRST issue order ----------------
// grid (bh=64, qt=8), block 256 = 4 waves, 2 blocks/CU. Wave owns 64 q-rows (nq=2).
// r17 post-mortem: EXP_PV(t) before S_TILE(t+1) defeats the pipeline — waves issue
// IN ORDER, so VALU work ahead of the MFMAs in the stream can't overlap them, and
// exp2 stalled on the just-issued S(t) chain (VGPR=116 proved only one st live).
// Fix: issue S_TILE(t+1) FIRST, then EXP_PV(t). st(t) is then a full iteration old
// (no stall), and exp/pack VALU runs while the matrix pipe digests S(t+1). Both st
// arrays live -> ~180 VGPR, still fine at 2 waves/SIMD.
// K double-buffered LDS (16KB), V TRIPLE-buffered (24KB, staging runs 2 tiles ahead).
// Buffer safety per iter t (barrier first): stage(t+2) writes K-buf t&1 / V-slot
// (t+2)%3 — last read at iter t-1, drained by this barrier; S_TILE reads K-buf
// (t+1)&1 (disjoint); EXP_PV reads V-slot t%3 (disjoint).
// S^T = mfma_32x32x16(K, Q): C/D col=l31(q), row=(r&3)+8*(r>>2)+4*hf (k).
// P redistribution to PV B-frag = lane<->lane+32 at same l31 (T12).

#define S_TILE(stD, bK)                                                             \
    do {                                                                            \
        bf16x8 kfm[2][4];                                                           \
        _Pragma("unroll")                                                           \
        for (int m_ = 0; m_ < 2; ++m_) {                                            \
            const int row_ = m_ * 32 + l31;                                         \
            _Pragma("unroll")                                                       \
            for (int dc_ = 0; dc_ < 4; ++dc_)                                       \
                kfm[m_][dc_] = ld16B(&(bK)[row_ * 64 + (((dc_ * 2 + hf) ^ l7) * 8)]); \
        }                                                                           \
        __builtin_amdgcn_s_setprio(1);                                              \
        _Pragma("unroll")                                                           \
        for (int m_ = 0; m_ < 2; ++m_)                                              \
            _Pragma("unroll")                                                       \
            for (int nq_ = 0; nq_ < 2; ++nq_)                                       \
                stD[m_][nq_] = __builtin_amdgcn_mfma_f32_32x32x16_bf16(kfm[m_][0], qf[nq_][0], fz, 0, 0, 0); \
        _Pragma("unroll")                                                           \
        for (int dc_ = 1; dc_ < 4; ++dc_)                                           \
            _Pragma("unroll")                                                       \
            for (int m_ = 0; m_ < 2; ++m_)                                          \
                _Pragma("unroll")                                                   \
                for (int nq_ = 0; nq_ < 2; ++nq_)                                   \
                    stD[m_][nq_] = __builtin_amdgcn_mfma_f32_32x32x16_bf16(kfm[m_][dc_], qf[nq_][dc_], stD[m_][nq_], 0, 0, 0); \
        __builtin_amdgcn_s_setprio(0);                                              \
    } while (0)

#define EXP_PV(stP, bV)                                                             \
    do {                                                                            \
        bf16x8 vfm[2][4];                                                           \
        _Pragma("unroll")                                                           \
        for (int dt_ = 0; dt_ < 2; ++dt_) {                                         \
            const int row_ = dt_ * 32 + l31;                                        \
            _Pragma("unroll")                                                       \
            for (int c_ = 0; c_ < 4; ++c_)                                          \
                vfm[dt_][c_] = ld16B(&(bV)[row_ * 64 + (((c_ * 2 + hf) ^ l7) * 8)]); \
        }                                                                           \
        _Pragma("unroll")                                                           \
        for (int c_ = 0; c_ < 4; ++c_) {                                            \
            const int m_ = c_ >> 1, r0_ = (c_ & 1) * 8;                             \
            _Pragma("unroll")                                                       \
            for (int nq_ = 0; nq_ < 2; ++nq_) {                                     \
                float e0 = __builtin_amdgcn_exp2f(stP[m_][nq_][r0_ + 0]);           \
                float e1 = __builtin_amdgcn_exp2f(stP[m_][nq_][r0_ + 1]);           \
                float e2 = __builtin_amdgcn_exp2f(stP[m_][nq_][r0_ + 2]);           \
                float e3 = __builtin_amdgcn_exp2f(stP[m_][nq_][r0_ + 3]);           \
                float e4 = __builtin_amdgcn_exp2f(stP[m_][nq_][r0_ + 4]);           \
                float e5 = __builtin_amdgcn_exp2f(stP[m_][nq_][r0_ + 5]);           \
                float e6 = __builtin_amdgcn_exp2f(stP[m_][nq_][r0_ + 6]);           \
                float e7 = __builtin_amdgcn_exp2f(stP[m_][nq_][r0_ + 7]);           \
                accS[nq_] += ((e0 + e1) + (e2 + e3)) + ((e4 + e5) + (e6 + e7));     \
                u32 Ua = cvtpk(e0, e1), Ub = cvtpk(e2, e3);                         \
                u32 Va = cvtpk(e4, e5), Vb = cvtpk(e6, e7);                         \
                u32x2 s0 = __builtin_amdgcn_permlane32_swap(Ua, Va, false, false);  \
                u32x2 s1 = __builtin_amdgcn_permlane32_swap(Ub, Vb, false, false);  \
                u32 dws_[4] = { s0.x, s1.x, s0.y, s1.y };                           \
                bf16x8 pB; __builtin_memcpy(&pB, dws_, 16);                         \
                __builtin_amdgcn_s_setprio(1);                                      \
                accO[0][nq_] = __builtin_amdgcn_mfma_f32_32x32x16_bf16(vfm[0][c_], pB, accO[0][nq_], 0, 0, 0); \
                accO[1][nq_] = __builtin_amdgcn_mfma_f32_32x32x16_bf16(vfm[1][c_], pB, accO[1][nq_], 0, 0, 0); \
                __builtin_amdgcn_s_setprio(0);                                      \
            }                                                                       \
        }                                                                           \
    } while (0)

#define ATTN_STEP(stP, stN, t)                                                      \
    do {                                                                            \
        __syncthreads();        /* tile t+1 staged; prior reads of reused bufs done */ \
        if ((t) < 30) { stageK((t) + 2); stageV((t) + 2); }                         \
        S_TILE(stN, sK + (((t) + 1) & 1) * 4096);   /* issue S(t+1) FIRST */        \
        EXP_PV(stP, sV + ((t) % 3) * 4096);         /* VALU overlaps S(t+1) */      \
    } while (0)

__global__ __launch_bounds__(256, 2) void attn_kernel(
    const u16* __restrict__ Q, const u16* __restrict__ K,
    const u16* __restrict__ Vt, u16* __restrict__ Y)
{
    const int bh = blockIdx.x, qt = blockIdx.y;
    const int tid = threadIdx.x;
    const int wave = tid >> 6, lane = tid & 63;
    const int hf = lane >> 5, l31 = lane & 31, l7 = l31 & 7;
    const int b = bh >> 4, h = bh & 15;

    // 40KB: K[2] x 8KB double buffer | V[3] x 8KB triple buffer. Epilogue reuses 32KB.
    __shared__ __align__(16) u16 smem[20480];
    u16* sK = smem;           // 2 * 4096 u16
    u16* sV = smem + 8192;    // 3 * 4096 u16

    // Q B-fragments (whole kernel in registers): qf[nq][dc]
    // B-frag: col=l31 (q row), k-dim d = dc*16 + hf*8 + j
    bf16x8 qf[2][4];
    {
        const size_t q0 = (size_t)(b * 2048 + qt * 256 + wave * 64) * 1024 + h * 64 + hf * 8;
        #pragma unroll
        for (int nq = 0; nq < 2; ++nq)
            #pragma unroll
            for (int dc = 0; dc < 4; ++dc)
                qf[nq][dc] = ld16B(Q + q0 + (size_t)(nq * 32 + l31) * 1024 + dc * 16);
    }

    const int r8 = lane >> 3;
    const int g7 = (lane & 7) ^ r8;                 // pre-swizzled global granule
    const u16* ksrc = K  + (size_t)(b * 2048 + wave * 16 + r8) * 1024 + h * 64 + g7 * 8;
    const u16* vsrc = Vt + ((size_t)(bh * 64 + wave * 16 + r8)) * 2048 + g7 * 8;

    auto stageK = [&](int t) {
        u16* dK = sK + (t & 1) * 4096 + wave * 1024;
        const u16* ks = ksrc + (size_t)t * 64 * 1024;
        async16(ks,            dK);
        async16(ks + 8 * 1024, dK + 512);
    };
    auto stageV = [&](int t) {
        u16* dV = sV + (t % 3) * 4096 + wave * 1024;
        const u16* vs = vsrc + (size_t)t * 64;
        async16(vs,            dV);
        async16(vs + 8 * 2048, dV + 512);
    };

    f32x16 accO[2][2];
    #pragma unroll
    for (int dt = 0; dt < 2; ++dt)
        #pragma unroll
        for (int nq = 0; nq < 2; ++nq)
            #pragma unroll
            for (int i = 0; i < 16; ++i) accO[dt][nq][i] = 0.f;
    float accS[2] = {0.f, 0.f};
    const f32x16 fz = {0.f,0.f,0.f,0.f,0.f,0.f,0.f,0.f,0.f,0.f,0.f,0.f,0.f,0.f,0.f,0.f};

    // prologue: tiles 0 and 1 staged; S(0) issued into stA
    stageK(0); stageV(0);
    __syncthreads();
    stageK(1); stageV(1);

    f32x16 stA[2][2], stB[2][2];
    S_TILE(stA, sK);   // K[0]

    // main pipeline: iter t = S(t+1) then exp/PV(t). 31 iterations, ping-pong st.
    #pragma unroll 1
    for (int t2 = 0; t2 < 30; t2 += 2) {
        ATTN_STEP(stA, stB, t2);
        ATTN_STEP(stB, stA, t2 + 1);
    }
    ATTN_STEP(stA, stB, 30);          // leaves st(31) in stB

    // drain: exp/PV(31). V(31) in slot 31%3=1, staged at t=29, drained at t=30 barrier.
    EXP_PV(stB, sV + (31 % 3) * 4096);

    // rowsum: lane holds k-halves with bit2==hf; partner is lane^32
    #pragma unroll
    for (int nq = 0; nq < 2; ++nq) accS[nq] += __shfl_xor(accS[nq], 32);
    const float inv0 = 1.f / accS[0], inv1 = 1.f / accS[1];

    __syncthreads();   // all waves done reading K/V buffers before smem reuse

    // epilogue: normalize, transpose O^T->O via per-wave 8KB LDS region
    u16* ep = smem + wave * 4096;   // 64 rows(q) x 64 cols(d), 16B-granule XOR swizzle
    #pragma unroll
    for (int nq = 0; nq < 2; ++nq) {
        const float inv = nq ? inv1 : inv0;
        const int row = nq * 32 + l31;
        #pragma unroll
        for (int dt = 0; dt < 2; ++dt)
            #pragma unroll
            for (int rq = 0; rq < 4; ++rq) {
                // accO reg r=rq*4+e -> d = dt*32 + rq*8 + 4*hf + e, q = row
                float v0 = accO[dt][nq][rq * 4 + 0] * inv;
                float v1 = accO[dt][nq][rq * 4 + 1] * inv;
                float v2 = accO[dt][nq][rq * 4 + 2] * inv;
                float v3 = accO[dt][nq][rq * 4 + 3] * inv;
                u32 dws[2] = { cvtpk(v0, v1), cvtpk(v2, v3) };
                const int g = dt * 4 + rq;
                __builtin_memcpy((char*)ep + row * 128 + ((g ^ l7) * 16) + hf * 8, dws, 8);
            }
    }
    // wave-private region: compiler orders ds write->read via lgkmcnt, no barrier needed
    const int rl = lane >> 3, cl = lane & 7;
    #pragma unroll
    for (int pass = 0; pass < 8; ++pass) {
        const int row = pass * 8 + rl;
        bf16x8 vrow = ld16B((const u16*)((const char*)ep + row * 128 + ((cl ^ (row & 7)) * 16)));
        const int t = qt * 256 + wave * 64 + row;
        __builtin_memcpy(Y + ((size_t)(b * 2048 + t)) * 1024 + h * 64 + cl * 8, &vrow, 16);
    }
}

// ---------------- launch ----------------
extern "C" void kernel_launch(void* const* d_in, const int* in_sizes, int n_in,
                              void* d_out, int out_size, void* d_ws, size_t ws_size,
                              hipStream_t stream)
{
    const float* x  = (const float*)d_in[0];
    const float* Wq = (const float*)d_in[1];
    const float* bq = (const float*)d_in[2];
    const float* Wk = (const float*)d_in[3];
    const float* bk = (const float*)d_in[4];
    const float* Wv = (const float*)d_in[5];
    const float* bv = (const float*)d_in[6];
    const float* Wo = (const float*)d_in[7];
    const float* bo = (const float*)d_in[8];
    float* out = (float*)d_out;

    const size_t NTOK = (size_t)8192 * 1024;
    const size_t WN   = (size_t)1024 * 1024;
    u16* xb  = (u16*)d_ws;
    u16* wqb = xb + NTOK;     // wq, wk, wv contiguous => [3072,1024] fused weight
    u16* wkb = wqb + WN;
    u16* wvb = wkb + WN;
    u16* wob = wvb + WN;
    u16* q   = wob + WN;
    u16* k   = q + NTOK;
    u16* vt  = k + NTOK;
    u16* y   = vt + NTOK;

    convert_kernel<<<dim3(12288), 256, 0, stream>>>(x, Wq, Wk, Wv, Wo, xb, wqb, wkb, wvb, wob);
    qkv_kernel<<<dim3(1536), 256, 0, stream>>>(xb, wqb, bq, bk, bv, q, k, vt);
    attn_kernel<<<dim3(64, 8), 256, 0, stream>>>(q, k, vt, y);
    proj_kernel<<<dim3(512), 256, 0, stream>>>(y, wob, bo, out);
}

// Round 19
// 266.933 us; speedup vs baseline: 1.0665x; 1.0665x over previous
//
#include <hip/hip_runtime.h>
#include <stdint.h>

// B=4, T=2048, C=1024, H=16, D=64.
// Inputs/outputs FP32 (per reference). Internal: bf16 MFMA, fp32 accum.

using u16 = unsigned short;
using u32 = unsigned int;
typedef __attribute__((ext_vector_type(8)))  __bf16 bf16x8;
typedef __attribute__((ext_vector_type(4)))  float  floatx4;
typedef __attribute__((ext_vector_type(16))) float  f32x16;
typedef __attribute__((ext_vector_type(2)))  unsigned int u32x2;

#define QSCALE 0.18033688011112043f   // 0.125 * log2(e), folded into Q projection

__device__ __forceinline__ u16 f2b(float f) {
    union { float f; u32 i; } x; x.f = f;
    return (u16)((x.i + 0x7fffu + ((x.i >> 16) & 1u)) >> 16);
}
__device__ __forceinline__ u32 fbits(float f) { union { float f; u32 i; } x; x.f = f; return x.i; }
// pack two fp32 -> (bf16(b)<<16)|bf16(a) : 2 adds + 1 v_perm
__device__ __forceinline__ u32 pkbf(float a, float b) {
    u32 ia = fbits(a) + 0x8000u, ib = fbits(b) + 0x8000u;
    return __builtin_amdgcn_perm(ib, ia, 0x07060302u);
}
// single-instruction RNE pack: D.lo=bf16(a), D.hi=bf16(b)
__device__ __forceinline__ u32 cvtpk(float a, float b) {
    u32 r; asm("v_cvt_pk_bf16_f32 %0, %1, %2" : "=v"(r) : "v"(a), "v"(b)); return r;
}
__device__ __forceinline__ bf16x8 ld16B(const u16* p) {
    bf16x8 v; __builtin_memcpy(&v, p, 16); return v;
}
__device__ __forceinline__ void async16(const u16* g, u16* l) {
    __builtin_amdgcn_global_load_lds((const __attribute__((address_space(1))) unsigned int*)g,
                                     (__attribute__((address_space(3))) unsigned int*)l,
                                     16, 0, 0);
}

// ---------------- convert fp32 -> bf16 (x + 4 weight matrices) ----------------
__global__ __launch_bounds__(256) void convert_kernel(
    const float* __restrict__ x,
    const float* __restrict__ Wq, const float* __restrict__ Wk,
    const float* __restrict__ Wv, const float* __restrict__ Wo,
    u16* __restrict__ xb, u16* __restrict__ wqb, u16* __restrict__ wkb,
    u16* __restrict__ wvb, u16* __restrict__ wob)
{
    size_t e = ((size_t)blockIdx.x * 256 + threadIdx.x) * 4;
    const float* src; u16* dst; size_t off;
    const size_t XN = (size_t)8 << 20;
    if (e < XN) { src = x; dst = xb; off = e; }
    else {
        size_t k = e - XN;
        int w = (int)(k >> 20);
        off = k & ((1u << 20) - 1);
        src = (w == 0) ? Wq : (w == 1) ? Wk : (w == 2) ? Wv : Wo;
        dst = (w == 0) ? wqb : (w == 1) ? wkb : (w == 2) ? wvb : wob;
    }
    float4 f = *(const float4*)(src + off);
    u32 dws[2] = { pkbf(f.x, f.y), pkbf(f.z, f.w) };
    __builtin_memcpy(dst + off, dws, 8);
}

// ---------------- shared GEMM K-loop: 2-phase double-buffer, BK=32, 32KB LDS ------------
// r18 change: old form was barrier -> stage -> drain-barrier (ZERO overlap) -> compute.
// T3-lite: stage(ph+1) issues BEFORE compute(ph), so the vmcnt drain at the barrier has
// ~16 MFMA + 8 ds_read of cover. Same LDS: each 8192-u16 array = two 128x32 buffers.
// Swizzle (4 granules/row): writer lane l -> slot l&3 gets source granule (l&3)^(r&3);
// reader slot quad^(ra&3) -> granule quad (k = k0 + quad*8 + j).
__device__ __forceinline__ void gemm_loop(const u16* __restrict__ A, const u16* __restrict__ W,
                                          int m0, int n0, floatx4 (&acc)[4][4],
                                          u16* __restrict__ sA, u16* __restrict__ sB)
{
    constexpr int K = 1024;
    const int tid  = threadIdx.x;
    const int wave = tid >> 6, lane = tid & 63;
    const int wr = wave >> 1, wc = wave & 1;
    const int quad = lane >> 4, l15 = lane & 15;

    #pragma unroll
    for (int i = 0; i < 4; ++i)
        #pragma unroll
        for (int j = 0; j < 4; ++j)
            acc[i][j] = (floatx4){0.f, 0.f, 0.f, 0.f};

    const int rstage = lane >> 2;                  // 16 rows per async16
    const int gs     = (lane & 3) ^ (rstage & 3);  // pre-swizzled source granule

    auto stage = [&](int buf, int ph) {
        const int k0 = ph * 32;
        #pragma unroll
        for (int j = 0; j < 2; ++j) {
            int r = wave * 32 + j * 16 + rstage;
            async16(A + (size_t)(m0 + r) * K + k0 + gs * 8,
                    sA + buf * 4096 + (wave * 32 + j * 16) * 32);
            async16(W + (size_t)(n0 + r) * K + k0 + gs * 8,
                    sB + buf * 4096 + (wave * 32 + j * 16) * 32);
        }
    };

    stage(0, 0);
    __syncthreads();                       // buffer 0 ready

    int buf = 0;
    #pragma unroll 1
    for (int ph = 0; ph < 32; ++ph) {
        if (ph < 31) stage(buf ^ 1, ph + 1);   // loads fly under this phase's compute
        const u16* bA = sA + buf * 4096;
        const u16* bB = sB + buf * 4096;
        bf16x8 af[4], bf[4];
        #pragma unroll
        for (int t = 0; t < 4; ++t) {
            int ra = wr * 64 + t * 16 + l15;
            af[t] = ld16B(&bA[ra * 32 + ((quad ^ (ra & 3)) * 8)]);
            int rb = wc * 64 + t * 16 + l15;
            bf[t] = ld16B(&bB[rb * 32 + ((quad ^ (rb & 3)) * 8)]);
        }
        #pragma unroll
        for (int mt = 0; mt < 4; ++mt)
            #pragma unroll
            for (int nt = 0; nt < 4; ++nt)
                acc[mt][nt] = __builtin_amdgcn_mfma_f32_16x16x32_bf16(af[mt], bf[nt], acc[mt][nt], 0, 0, 0);
        __syncthreads();                   // drains vmcnt; next buffer ready
        buf ^= 1;
    }
}

// ---------------- fused QKV projection ----------------
// Wcat = [3072,1024]. 1-D grid 1536; XCD-partitioned swizzle: each XCD owns 8 m-tiles
// (x slice 2 MB -> L2-resident), n varies per slot.
// z=0: Q row-major * QSCALE; z=1: K row-major; z=2: Vt [bh*64+d][2048].
__global__ __launch_bounds__(256, 3) void qkv_kernel(
    const u16* __restrict__ x, const u16* __restrict__ Wcat,
    const float* __restrict__ bq, const float* __restrict__ bk, const float* __restrict__ bv,
    u16* __restrict__ q, u16* __restrict__ k, u16* __restrict__ vt)
{
    __shared__ __align__(16) u16 sA[128 * 64];   // two 128x32 buffers
    __shared__ __align__(16) u16 sB[128 * 64];
    const int id = blockIdx.x;
    const int xcd = id & 7, slot = id >> 3;        // 192 slots per XCD
    const int m0 = (xcd * 8 + (slot & 7)) * 128;   // m-tile 0..63
    const int n0 = (slot >> 3) * 128;              // n-tile 0..23
    floatx4 acc[4][4];
    gemm_loop(x, Wcat, m0, n0, acc, sA, sB);

    const int tid = threadIdx.x;
    const int wave = tid >> 6, lane = tid & 63;
    const int wr = wave >> 1, wc = wave & 1;
    const int quad = lane >> 4, l15 = lane & 15;

    const int z = n0 >> 10;
    const float* bb = (z == 0) ? bq : (z == 1) ? bk : bv;
    const float scale = (z == 0) ? QSCALE : 1.0f;
    u16* o = (z == 0) ? q : k;

    #pragma unroll
    for (int nt = 0; nt < 4; ++nt) {
        int col  = n0 + wc * 64 + nt * 16 + l15;   // in [0,3072)
        int c    = col & 1023;
        float bv_ = bb[c];
        #pragma unroll
        for (int mt = 0; mt < 4; ++mt) {
            int row0 = m0 + wr * 64 + mt * 16 + quad * 4;
            if (z == 2) {
                // Vt: addr = ((b*16+h)*64+d)*2048 + t, t=row contiguous -> 8B store
                float v0 = acc[mt][nt][0] + bv_, v1 = acc[mt][nt][1] + bv_;
                float v2 = acc[mt][nt][2] + bv_, v3 = acc[mt][nt][3] + bv_;
                u32 dws[2] = { pkbf(v0, v1), pkbf(v2, v3) };
                int b = row0 >> 11, t0 = row0 & 2047;
                size_t idx = ((size_t)((b * 16 + (c >> 6)) * 64 + (c & 63)) * 2048) + t0;
                __builtin_memcpy(vt + idx, dws, 8);
            } else {
                #pragma unroll
                for (int r = 0; r < 4; ++r) {
                    float v = (acc[mt][nt][r] + bv_) * scale;
                    o[(size_t)(row0 + r) * 1024 + c] = f2b(v);
                }
            }
        }
    }
}

// ---------------- output projection ----------------
__global__ __launch_bounds__(256, 3) void proj_kernel(
    const u16* __restrict__ y, const u16* __restrict__ Wo, const float* __restrict__ bo,
    float* __restrict__ out)
{
    __shared__ __align__(16) u16 sA[128 * 64];   // two 128x32 buffers
    __shared__ __align__(16) u16 sB[128 * 64];
    const int id = blockIdx.x;
    const int xcd = id & 7, slot = id >> 3;        // 64 slots per XCD
    const int m0 = (xcd * 8 + (slot & 7)) * 128;   // m-tile 0..63
    const int n0 = (slot >> 3) * 128;              // n-tile 0..7
    floatx4 acc[4][4];
    gemm_loop(y, Wo, m0, n0, acc, sA, sB);

    const int tid = threadIdx.x;
    const int wave = tid >> 6, lane = tid & 63;
    const int wr = wave >> 1, wc = wave & 1;
    const int quad = lane >> 4, l15 = lane & 15;

    #pragma unroll
    for (int nt = 0; nt < 4; ++nt) {
        int col = n0 + wc * 64 + nt * 16 + l15;
        float bv_ = bo[col];
        #pragma unroll
        for (int mt = 0; mt < 4; ++mt) {
            int row0 = m0 + wr * 64 + mt * 16 + quad * 4;
            #pragma unroll
            for (int r = 0; r < 4; ++r)
                out[(size_t)(row0 + r) * 1024 + col] = acc[mt][nt][r] + bv_;
        }
    }
}

// ---------------- Flash attention: r1 structure (measured 82.7us — best) ----------------
// grid (bh=64, qt=8), block 256 = 4 waves. Wave owns 64 q-rows (2 q-tiles of 32).
// r18 lesson: double-st pipeline needs ~290 VGPR -> spills (WRITE_SIZE 16->56MB), 112us.
// r17 (EXP_PV-first pipeline): 87.8us. r1 simple order: 82.7us — reverted to r1 verbatim.
// Q row-major [8192,1024] pre-scaled by 0.125*log2e; K row-major; Vt [bh*64+d, 2048].
// S^T = mfma_32x32x16(K, Q): C/D col=l31(q), row=(r&3)+8*(r>>2)+4*half (k).
// P redistribution to PV B-frag = lane<->lane+32 at same l31 (T12):
//   d0,d2 = permlane32_swap(cvtpk(e0,e1), cvtpk(e4,e5)); d1,d3 = swap(cvtpk(e2,e3), cvtpk(e6,e7)).
__global__ __launch_bounds__(256, 2) void attn_kernel(
    const u16* __restrict__ Q, const u16* __restrict__ K,
    const u16* __restrict__ Vt, u16* __restrict__ Y)
{
    const int bh = blockIdx.x, qt = blockIdx.y;
    const int tid = threadIdx.x;
    const int wave = tid >> 6, lane = tid & 63;
    const int hf = lane >> 5, l31 = lane & 31, l7 = l31 & 7;
    const int b = bh >> 4, h = bh & 15;

    // [Kbuf0 | Kbuf1 | Vbuf0 | Vbuf1], each 64x64 u16 (8KB), XOR-swizzled 16B granules
    __shared__ __align__(16) u16 smem[16384];

    // Q B-fragments (whole kernel in registers): qf[nq][dc]
    // B-frag: col=l31 (q row), k-dim d = dc*16 + hf*8 + j
    bf16x8 qf[2][4];
    {
        const size_t q0 = (size_t)(b * 2048 + qt * 256 + wave * 64) * 1024 + h * 64 + hf * 8;
        #pragma unroll
        for (int nq = 0; nq < 2; ++nq)
            #pragma unroll
            for (int dc = 0; dc < 4; ++dc)
                qf[nq][dc] = ld16B(Q + q0 + (size_t)(nq * 32 + l31) * 1024 + dc * 16);
    }

    const int r8 = lane >> 3;
    const int g7 = (lane & 7) ^ r8;                 // pre-swizzled global granule
    const u16* ksrc = K  + (size_t)(b * 2048 + wave * 16 + r8) * 1024 + h * 64 + g7 * 8;
    const u16* vsrc = Vt + ((size_t)(bh * 64 + wave * 16 + r8)) * 2048 + g7 * 8;

    f32x16 accO[2][2];
    #pragma unroll
    for (int dt = 0; dt < 2; ++dt)
        #pragma unroll
        for (int nq = 0; nq < 2; ++nq)
            #pragma unroll
            for (int i = 0; i < 16; ++i) accO[dt][nq][i] = 0.f;
    float accS[2] = {0.f, 0.f};

    // prologue: stage tile 0 into buf 0
    {
        u16* dK = smem + wave * 1024;
        u16* dV = smem + 8192 + wave * 1024;
        async16(ksrc,            dK);
        async16(ksrc + 8 * 1024, dK + 512);
        async16(vsrc,            dV);
        async16(vsrc + 8 * 2048, dV + 512);
    }
    __syncthreads();

    #pragma unroll 1
    for (int kt = 0; kt < 32; ++kt) {
        const int cur = kt & 1;
        if (kt < 31) {
            u16* dK = smem + (cur ^ 1) * 4096 + wave * 1024;
            u16* dV = smem + 8192 + (cur ^ 1) * 4096 + wave * 1024;
            const u16* ks = ksrc + (size_t)(kt + 1) * 64 * 1024;
            const u16* vs = vsrc + (size_t)(kt + 1) * 64;
            async16(ks,            dK);
            async16(ks + 8 * 1024, dK + 512);
            async16(vs,            dV);
            async16(vs + 8 * 2048, dV + 512);
        }
        const u16* bK = smem + cur * 4096;
        const u16* bV = smem + 8192 + cur * 4096;

        // K A-fragments: whole 64x64 tile (rows m*32+l31, d-granule (dc*2+hf)^l7)
        bf16x8 kfm[2][4];
        #pragma unroll
        for (int m = 0; m < 2; ++m) {
            const int row = m * 32 + l31;
            #pragma unroll
            for (int dc = 0; dc < 4; ++dc)
                kfm[m][dc] = ld16B(&bK[row * 64 + (((dc * 2 + hf) ^ l7) * 8)]);
        }

        // S^T phase: 16 MFMA, 4 independent accumulate chains
        f32x16 st[2][2];
        #pragma unroll
        for (int m = 0; m < 2; ++m)
            #pragma unroll
            for (int nq = 0; nq < 2; ++nq)
                #pragma unroll
                for (int i = 0; i < 16; ++i) st[m][nq][i] = 0.f;
        __builtin_amdgcn_s_setprio(1);
        #pragma unroll
        for (int dc = 0; dc < 4; ++dc)
            #pragma unroll
            for (int m = 0; m < 2; ++m)
                #pragma unroll
                for (int nq = 0; nq < 2; ++nq)
                    st[m][nq] = __builtin_amdgcn_mfma_f32_32x32x16_bf16(kfm[m][dc], qf[nq][dc], st[m][nq], 0, 0, 0);
        __builtin_amdgcn_s_setprio(0);

        // V A-fragments (issued here: LDS latency hides under exp/pack)
        bf16x8 vfm[2][4];
        #pragma unroll
        for (int dt = 0; dt < 2; ++dt) {
            const int row = dt * 32 + l31;
            #pragma unroll
            for (int c = 0; c < 4; ++c)
                vfm[dt][c] = ld16B(&bV[row * 64 + (((c * 2 + hf) ^ l7) * 8)]);
        }

        // exp2 -> pack -> permlane32_swap -> PV, per (c, nq); rowsum via f32 adds
        #pragma unroll
        for (int c = 0; c < 4; ++c) {
            const int m = c >> 1, r0 = (c & 1) * 8;
            #pragma unroll
            for (int nq = 0; nq < 2; ++nq) {
                float e0 = __builtin_amdgcn_exp2f(st[m][nq][r0 + 0]);
                float e1 = __builtin_amdgcn_exp2f(st[m][nq][r0 + 1]);
                float e2 = __builtin_amdgcn_exp2f(st[m][nq][r0 + 2]);
                float e3 = __builtin_amdgcn_exp2f(st[m][nq][r0 + 3]);
                float e4 = __builtin_amdgcn_exp2f(st[m][nq][r0 + 4]);
                float e5 = __builtin_amdgcn_exp2f(st[m][nq][r0 + 5]);
                float e6 = __builtin_amdgcn_exp2f(st[m][nq][r0 + 6]);
                float e7 = __builtin_amdgcn_exp2f(st[m][nq][r0 + 7]);
                accS[nq] += ((e0 + e1) + (e2 + e3)) + ((e4 + e5) + (e6 + e7));
                u32 Ua = cvtpk(e0, e1), Ub = cvtpk(e2, e3);
                u32 Va = cvtpk(e4, e5), Vb = cvtpk(e6, e7);
                u32x2 s0 = __builtin_amdgcn_permlane32_swap(Ua, Va, false, false);
                u32x2 s1 = __builtin_amdgcn_permlane32_swap(Ub, Vb, false, false);
                u32 dws[4] = { s0.x, s1.x, s0.y, s1.y };
                bf16x8 pB; __builtin_memcpy(&pB, dws, 16);
                __builtin_amdgcn_s_setprio(1);
                accO[0][nq] = __builtin_amdgcn_mfma_f32_32x32x16_bf16(vfm[0][c], pB, accO[0][nq], 0, 0, 0);
                accO[1][nq] = __builtin_amdgcn_mfma_f32_32x32x16_bf16(vfm[1][c], pB, accO[1][nq], 0, 0, 0);
                __builtin_amdgcn_s_setprio(0);
            }
        }
        __syncthreads();
    }

    // rowsum: lane holds k-halves with bit2==hf; partner is lane^32
    #pragma unroll
    for (int nq = 0; nq < 2; ++nq) accS[nq] += __shfl_xor(accS[nq], 32);
    const float inv0 = 1.f / accS[0], inv1 = 1.f / accS[1];

    // epilogue: normalize, transpose O^T->O via per-wave 8KB LDS region (reuses K/V bufs)
    u16* ep = smem + wave * 4096;   // 64 rows(q) x 64 cols(d), 16B-granule XOR swizzle
    #pragma unroll
    for (int nq = 0; nq < 2; ++nq) {
        const float inv = nq ? inv1 : inv0;
        const int row = nq * 32 + l31;
        #pragma unroll
        for (int dt = 0; dt < 2; ++dt)
            #pragma unroll
            for (int rq = 0; rq < 4; ++rq) {
                // accO reg r=rq*4+e -> d = dt*32 + rq*8 + 4*hf + e, q = row
                float v0 = accO[dt][nq][rq * 4 + 0] * inv;
                float v1 = accO[dt][nq][rq * 4 + 1] * inv;
                float v2 = accO[dt][nq][rq * 4 + 2] * inv;
                float v3 = accO[dt][nq][rq * 4 + 3] * inv;
                u32 dws[2] = { cvtpk(v0, v1), cvtpk(v2, v3) };
                const int g = dt * 4 + rq;
                __builtin_memcpy((char*)ep + row * 128 + ((g ^ l7) * 16) + hf * 8, dws, 8);
            }
    }
    // per-wave region: no cross-wave hazard; compiler orders ds write->read via lgkmcnt
    const int rl = lane >> 3, cl = lane & 7;
    #pragma unroll
    for (int pass = 0; pass < 8; ++pass) {
        const int row = pass * 8 + rl;
        bf16x8 vrow = ld16B((const u16*)((const char*)ep + row * 128 + ((cl ^ (row & 7)) * 16)));
        const int t = qt * 256 + wave * 64 + row;
        __builtin_memcpy(Y + ((size_t)(b * 2048 + t)) * 1024 + h * 64 + cl * 8, &vrow, 16);
    }
}

// ---------------- launch ----------------
extern "C" void kernel_launch(void* const* d_in, const int* in_sizes, int n_in,
                              void* d_out, int out_size, void* d_ws, size_t ws_size,
                              hipStream_t stream)
{
    const float* x  = (const float*)d_in[0];
    const float* Wq = (const float*)d_in[1];
    const float* bq = (const float*)d_in[2];
    const float* Wk = (const float*)d_in[3];
    const float* bk = (const float*)d_in[4];
    const float* Wv = (const float*)d_in[5];
    const float* bv = (const float*)d_in[6];
    const float* Wo = (const float*)d_in[7];
    const float* bo = (const float*)d_in[8];
    float* out = (float*)d_out;

    const size_t NTOK = (size_t)8192 * 1024;
    const size_t WN   = (size_t)1024 * 1024;
    u16* xb  = (u16*)d_ws;
    u16* wqb = xb + NTOK;     // wq, wk, wv contiguous => [3072,1024] fused weight
    u16* wkb = wqb + WN;
    u16* wvb = wkb + WN;
    u16* wob = wvb + WN;
    u16* q   = wob + WN;
    u16* k   = q + NTOK;
    u16* vt  = k + NTOK;
    u16* y   = vt + NTOK;

    convert_kernel<<<dim3(12288), 256, 0, stream>>>(x, Wq, Wk, Wv, Wo, xb, wqb, wkb, wvb, wob);
    qkv_kernel<<<dim3(1536), 256, 0, stream>>>(xb, wqb, bq, bk, bv, q, k, vt);
    attn_kernel<<<dim3(64, 8), 256, 0, stream>>>(q, k, vt, y);
    proj_kernel<<<dim3(512), 256, 0, stream>>>(y, wob, bo, out);
}

// Round 20
// 256.589 us; speedup vs baseline: 1.1094x; 1.0403x over previous
//
#include <hip/hip_runtime.h>
#include <stdint.h>

// B=4, T=2048, C=1024, H=16, D=64.
// Inputs/outputs FP32 (per reference). Internal: bf16 MFMA, fp32 accum.

using u16 = unsigned short;
using u32 = unsigned int;
typedef __attribute__((ext_vector_type(8)))  __bf16 bf16x8;
typedef __attribute__((ext_vector_type(4)))  float  floatx4;
typedef __attribute__((ext_vector_type(16))) float  f32x16;
typedef __attribute__((ext_vector_type(2)))  unsigned int u32x2;

#define QSCALE 0.18033688011112043f   // 0.125 * log2(e), folded into Q projection

__device__ __forceinline__ u16 f2b(float f) {
    union { float f; u32 i; } x; x.f = f;
    return (u16)((x.i + 0x7fffu + ((x.i >> 16) & 1u)) >> 16);
}
__device__ __forceinline__ u32 fbits(float f) { union { float f; u32 i; } x; x.f = f; return x.i; }
// pack two fp32 -> (bf16(b)<<16)|bf16(a) : 2 adds + 1 v_perm
__device__ __forceinline__ u32 pkbf(float a, float b) {
    u32 ia = fbits(a) + 0x8000u, ib = fbits(b) + 0x8000u;
    return __builtin_amdgcn_perm(ib, ia, 0x07060302u);
}
// single-instruction RNE pack: D.lo=bf16(a), D.hi=bf16(b)
__device__ __forceinline__ u32 cvtpk(float a, float b) {
    u32 r; asm("v_cvt_pk_bf16_f32 %0, %1, %2" : "=v"(r) : "v"(a), "v"(b)); return r;
}
__device__ __forceinline__ bf16x8 ld16B(const u16* p) {
    bf16x8 v; __builtin_memcpy(&v, p, 16); return v;
}
__device__ __forceinline__ void async16(const u16* g, u16* l) {
    __builtin_amdgcn_global_load_lds((const __attribute__((address_space(1))) unsigned int*)g,
                                     (__attribute__((address_space(3))) unsigned int*)l,
                                     16, 0, 0);
}

// ---------------- convert fp32 -> bf16 (x + 4 weight matrices) ----------------
__global__ __launch_bounds__(256) void convert_kernel(
    const float* __restrict__ x,
    const float* __restrict__ Wq, const float* __restrict__ Wk,
    const float* __restrict__ Wv, const float* __restrict__ Wo,
    u16* __restrict__ xb, u16* __restrict__ wqb, u16* __restrict__ wkb,
    u16* __restrict__ wvb, u16* __restrict__ wob)
{
    size_t e = ((size_t)blockIdx.x * 256 + threadIdx.x) * 4;
    const float* src; u16* dst; size_t off;
    const size_t XN = (size_t)8 << 20;
    if (e < XN) { src = x; dst = xb; off = e; }
    else {
        size_t k = e - XN;
        int w = (int)(k >> 20);
        off = k & ((1u << 20) - 1);
        src = (w == 0) ? Wq : (w == 1) ? Wk : (w == 2) ? Wv : Wo;
        dst = (w == 0) ? wqb : (w == 1) ? wkb : (w == 2) ? wvb : wob;
    }
    float4 f = *(const float4*)(src + off);
    u32 dws[2] = { pkbf(f.x, f.y), pkbf(f.z, f.w) };
    __builtin_memcpy(dst + off, dws, 8);
}

// ---------------- shared GEMM K-loop: single-buffer 32KB (m97 form), occupancy-first ----------
// acc = A[128 rows m0..] . W[128 rows n0..]^T, K=1024, BK=64, XOR-swizzled LDS.
// r19 lesson: BK=32 2-phase halved the staging coalescing granule (64B rows, 2x requests)
// and regressed qkv+proj ~26us. Reverted to the measured-best BK=64 m97 form.
__device__ __forceinline__ void gemm_loop(const u16* __restrict__ A, const u16* __restrict__ W,
                                          int m0, int n0, floatx4 (&acc)[4][4],
                                          u16* __restrict__ sA, u16* __restrict__ sB)
{
    constexpr int K = 1024;
    const int tid  = threadIdx.x;
    const int wave = tid >> 6, lane = tid & 63;
    const int wr = wave >> 1, wc = wave & 1;
    const int quad = lane >> 4, l15 = lane & 15;

    #pragma unroll
    for (int i = 0; i < 4; ++i)
        #pragma unroll
        for (int j = 0; j < 4; ++j)
            acc[i][j] = (floatx4){0.f, 0.f, 0.f, 0.f};

    const int rstage = lane >> 3;              // 8 rows per async16
    const int gstage = lane & 7;

    #pragma unroll 1
    for (int kb = 0; kb < 16; ++kb) {
        __syncthreads();                       // previous tile fully consumed
        const int k0 = kb * 64;
        #pragma unroll
        for (int j = 0; j < 4; ++j) {
            int r  = wave * 32 + j * 8 + rstage;
            int kg = gstage ^ (r & 7);
            async16(A + (size_t)(m0 + r) * K + k0 + kg * 8, &sA[(wave * 32 + j * 8) * 64]);
            async16(W + (size_t)(n0 + r) * K + k0 + kg * 8, &sB[(wave * 32 + j * 8) * 64]);
        }
        __syncthreads();                       // drains vmcnt (global_load_lds)

        #pragma unroll
        for (int kk = 0; kk < 2; ++kk) {
            bf16x8 af[4], bf[4];
            const int kg = kk * 4 + quad;
            #pragma unroll
            for (int t = 0; t < 4; ++t) {
                int ra = wr * 64 + t * 16 + l15;
                af[t] = ld16B(&sA[ra * 64 + ((kg ^ (ra & 7)) * 8)]);
                int rb = wc * 64 + t * 16 + l15;
                bf[t] = ld16B(&sB[rb * 64 + ((kg ^ (rb & 7)) * 8)]);
            }
            #pragma unroll
            for (int mt = 0; mt < 4; ++mt)
                #pragma unroll
                for (int nt = 0; nt < 4; ++nt)
                    acc[mt][nt] = __builtin_amdgcn_mfma_f32_16x16x32_bf16(af[mt], bf[nt], acc[mt][nt], 0, 0, 0);
        }
    }
}

// ---------------- fused QKV projection ----------------
// Wcat = [3072,1024]. 1-D grid 1536; XCD-partitioned swizzle: each XCD owns 8 m-tiles
// (x slice 2 MB -> L2-resident), n varies per slot.
// z=0: Q row-major * QSCALE; z=1: K row-major; z=2: Vt [bh*64+d][2048].
__global__ __launch_bounds__(256, 3) void qkv_kernel(
    const u16* __restrict__ x, const u16* __restrict__ Wcat,
    const float* __restrict__ bq, const float* __restrict__ bk, const float* __restrict__ bv,
    u16* __restrict__ q, u16* __restrict__ k, u16* __restrict__ vt)
{
    __shared__ __align__(16) u16 sA[128 * 64];
    __shared__ __align__(16) u16 sB[128 * 64];
    const int id = blockIdx.x;
    const int xcd = id & 7, slot = id >> 3;        // 192 slots per XCD
    const int m0 = (xcd * 8 + (slot & 7)) * 128;   // m-tile 0..63
    const int n0 = (slot >> 3) * 128;              // n-tile 0..23
    floatx4 acc[4][4];
    gemm_loop(x, Wcat, m0, n0, acc, sA, sB);

    const int tid = threadIdx.x;
    const int wave = tid >> 6, lane = tid & 63;
    const int wr = wave >> 1, wc = wave & 1;
    const int quad = lane >> 4, l15 = lane & 15;

    const int z = n0 >> 10;
    const float* bb = (z == 0) ? bq : (z == 1) ? bk : bv;
    const float scale = (z == 0) ? QSCALE : 1.0f;
    u16* o = (z == 0) ? q : k;

    #pragma unroll
    for (int nt = 0; nt < 4; ++nt) {
        int col  = n0 + wc * 64 + nt * 16 + l15;   // in [0,3072)
        int c    = col & 1023;
        float bv_ = bb[c];
        #pragma unroll
        for (int mt = 0; mt < 4; ++mt) {
            int row0 = m0 + wr * 64 + mt * 16 + quad * 4;
            if (z == 2) {
                // Vt: addr = ((b*16+h)*64+d)*2048 + t, t=row contiguous -> 8B store
                float v0 = acc[mt][nt][0] + bv_, v1 = acc[mt][nt][1] + bv_;
                float v2 = acc[mt][nt][2] + bv_, v3 = acc[mt][nt][3] + bv_;
                u32 dws[2] = { pkbf(v0, v1), pkbf(v2, v3) };
                int b = row0 >> 11, t0 = row0 & 2047;
                size_t idx = ((size_t)((b * 16 + (c >> 6)) * 64 + (c & 63)) * 2048) + t0;
                __builtin_memcpy(vt + idx, dws, 8);
            } else {
                #pragma unroll
                for (int r = 0; r < 4; ++r) {
                    float v = (acc[mt][nt][r] + bv_) * scale;
                    o[(size_t)(row0 + r) * 1024 + c] = f2b(v);
                }
            }
        }
    }
}

// ---------------- output projection ----------------
__global__ __launch_bounds__(256, 3) void proj_kernel(
    const u16* __restrict__ y, const u16* __restrict__ Wo, const float* __restrict__ bo,
    float* __restrict__ out)
{
    __shared__ __align__(16) u16 sA[128 * 64];
    __shared__ __align__(16) u16 sB[128 * 64];
    const int id = blockIdx.x;
    const int xcd = id & 7, slot = id >> 3;        // 64 slots per XCD
    const int m0 = (xcd * 8 + (slot & 7)) * 128;   // m-tile 0..63
    const int n0 = (slot >> 3) * 128;              // n-tile 0..7
    floatx4 acc[4][4];
    gemm_loop(y, Wo, m0, n0, acc, sA, sB);

    const int tid = threadIdx.x;
    const int wave = tid >> 6, lane = tid & 63;
    const int wr = wave >> 1, wc = wave & 1;
    const int quad = lane >> 4, l15 = lane & 15;

    #pragma unroll
    for (int nt = 0; nt < 4; ++nt) {
        int col = n0 + wc * 64 + nt * 16 + l15;
        float bv_ = bo[col];
        #pragma unroll
        for (int mt = 0; mt < 4; ++mt) {
            int row0 = m0 + wr * 64 + mt * 16 + quad * 4;
            #pragma unroll
            for (int r = 0; r < 4; ++r)
                out[(size_t)(row0 + r) * 1024 + col] = acc[mt][nt][r] + bv_;
        }
    }
}

// ---------------- Flash attention: r1 structure (measured 82.7-83.4us — best) ------------
// grid (bh=64, qt=8), block 256 = 4 waves. Wave owns 64 q-rows (2 q-tiles of 32).
// Pipeline experiments (r17 EXP_PV-first: 87.8; r18 S-first: 112, VGPR spill) both lost
// to this simple order. Serial-sum regime (MFMA 29 + VALU 33 + LDS 19us) is this
// structure's source-level floor.
// Q row-major [8192,1024] pre-scaled by 0.125*log2e; K row-major; Vt [bh*64+d, 2048].
// S^T = mfma_32x32x16(K, Q): C/D col=l31(q), row=(r&3)+8*(r>>2)+4*half (k).
// P redistribution to PV B-frag = lane<->lane+32 at same l31 (T12):
//   d0,d2 = permlane32_swap(cvtpk(e0,e1), cvtpk(e4,e5)); d1,d3 = swap(cvtpk(e2,e3), cvtpk(e6,e7)).
__global__ __launch_bounds__(256, 2) void attn_kernel(
    const u16* __restrict__ Q, const u16* __restrict__ K,
    const u16* __restrict__ Vt, u16* __restrict__ Y)
{
    const int bh = blockIdx.x, qt = blockIdx.y;
    const int tid = threadIdx.x;
    const int wave = tid >> 6, lane = tid & 63;
    const int hf = lane >> 5, l31 = lane & 31, l7 = l31 & 7;
    const int b = bh >> 4, h = bh & 15;

    // [Kbuf0 | Kbuf1 | Vbuf0 | Vbuf1], each 64x64 u16 (8KB), XOR-swizzled 16B granules
    __shared__ __align__(16) u16 smem[16384];

    // Q B-fragments (whole kernel in registers): qf[nq][dc]
    // B-frag: col=l31 (q row), k-dim d = dc*16 + hf*8 + j
    bf16x8 qf[2][4];
    {
        const size_t q0 = (size_t)(b * 2048 + qt * 256 + wave * 64) * 1024 + h * 64 + hf * 8;
        #pragma unroll
        for (int nq = 0; nq < 2; ++nq)
            #pragma unroll
            for (int dc = 0; dc < 4; ++dc)
                qf[nq][dc] = ld16B(Q + q0 + (size_t)(nq * 32 + l31) * 1024 + dc * 16);
    }

    const int r8 = lane >> 3;
    const int g7 = (lane & 7) ^ r8;                 // pre-swizzled global granule
    const u16* ksrc = K  + (size_t)(b * 2048 + wave * 16 + r8) * 1024 + h * 64 + g7 * 8;
    const u16* vsrc = Vt + ((size_t)(bh * 64 + wave * 16 + r8)) * 2048 + g7 * 8;

    f32x16 accO[2][2];
    #pragma unroll
    for (int dt = 0; dt < 2; ++dt)
        #pragma unroll
        for (int nq = 0; nq < 2; ++nq)
            #pragma unroll
            for (int i = 0; i < 16; ++i) accO[dt][nq][i] = 0.f;
    float accS[2] = {0.f, 0.f};

    // prologue: stage tile 0 into buf 0
    {
        u16* dK = smem + wave * 1024;
        u16* dV = smem + 8192 + wave * 1024;
        async16(ksrc,            dK);
        async16(ksrc + 8 * 1024, dK + 512);
        async16(vsrc,            dV);
        async16(vsrc + 8 * 2048, dV + 512);
    }
    __syncthreads();

    #pragma unroll 1
    for (int kt = 0; kt < 32; ++kt) {
        const int cur = kt & 1;
        if (kt < 31) {
            u16* dK = smem + (cur ^ 1) * 4096 + wave * 1024;
            u16* dV = smem + 8192 + (cur ^ 1) * 4096 + wave * 1024;
            const u16* ks = ksrc + (size_t)(kt + 1) * 64 * 1024;
            const u16* vs = vsrc + (size_t)(kt + 1) * 64;
            async16(ks,            dK);
            async16(ks + 8 * 1024, dK + 512);
            async16(vs,            dV);
            async16(vs + 8 * 2048, dV + 512);
        }
        const u16* bK = smem + cur * 4096;
        const u16* bV = smem + 8192 + cur * 4096;

        // K A-fragments: whole 64x64 tile (rows m*32+l31, d-granule (dc*2+hf)^l7)
        bf16x8 kfm[2][4];
        #pragma unroll
        for (int m = 0; m < 2; ++m) {
            const int row = m * 32 + l31;
            #pragma unroll
            for (int dc = 0; dc < 4; ++dc)
                kfm[m][dc] = ld16B(&bK[row * 64 + (((dc * 2 + hf) ^ l7) * 8)]);
        }

        // S^T phase: 16 MFMA, 4 independent accumulate chains
        f32x16 st[2][2];
        #pragma unroll
        for (int m = 0; m < 2; ++m)
            #pragma unroll
            for (int nq = 0; nq < 2; ++nq)
                #pragma unroll
                for (int i = 0; i < 16; ++i) st[m][nq][i] = 0.f;
        __builtin_amdgcn_s_setprio(1);
        #pragma unroll
        for (int dc = 0; dc < 4; ++dc)
            #pragma unroll
            for (int m = 0; m < 2; ++m)
                #pragma unroll
                for (int nq = 0; nq < 2; ++nq)
                    st[m][nq] = __builtin_amdgcn_mfma_f32_32x32x16_bf16(kfm[m][dc], qf[nq][dc], st[m][nq], 0, 0, 0);
        __builtin_amdgcn_s_setprio(0);

        // V A-fragments (issued here: LDS latency hides under exp/pack)
        bf16x8 vfm[2][4];
        #pragma unroll
        for (int dt = 0; dt < 2; ++dt) {
            const int row = dt * 32 + l31;
            #pragma unroll
            for (int c = 0; c < 4; ++c)
                vfm[dt][c] = ld16B(&bV[row * 64 + (((c * 2 + hf) ^ l7) * 8)]);
        }

        // exp2 -> pack -> permlane32_swap -> PV, per (c, nq); rowsum via f32 adds
        #pragma unroll
        for (int c = 0; c < 4; ++c) {
            const int m = c >> 1, r0 = (c & 1) * 8;
            #pragma unroll
            for (int nq = 0; nq < 2; ++nq) {
                float e0 = __builtin_amdgcn_exp2f(st[m][nq][r0 + 0]);
                float e1 = __builtin_amdgcn_exp2f(st[m][nq][r0 + 1]);
                float e2 = __builtin_amdgcn_exp2f(st[m][nq][r0 + 2]);
                float e3 = __builtin_amdgcn_exp2f(st[m][nq][r0 + 3]);
                float e4 = __builtin_amdgcn_exp2f(st[m][nq][r0 + 4]);
                float e5 = __builtin_amdgcn_exp2f(st[m][nq][r0 + 5]);
                float e6 = __builtin_amdgcn_exp2f(st[m][nq][r0 + 6]);
                float e7 = __builtin_amdgcn_exp2f(st[m][nq][r0 + 7]);
                accS[nq] += ((e0 + e1) + (e2 + e3)) + ((e4 + e5) + (e6 + e7));
                u32 Ua = cvtpk(e0, e1), Ub = cvtpk(e2, e3);
                u32 Va = cvtpk(e4, e5), Vb = cvtpk(e6, e7);
                u32x2 s0 = __builtin_amdgcn_permlane32_swap(Ua, Va, false, false);
                u32x2 s1 = __builtin_amdgcn_permlane32_swap(Ub, Vb, false, false);
                u32 dws[4] = { s0.x, s1.x, s0.y, s1.y };
                bf16x8 pB; __builtin_memcpy(&pB, dws, 16);
                __builtin_amdgcn_s_setprio(1);
                accO[0][nq] = __builtin_amdgcn_mfma_f32_32x32x16_bf16(vfm[0][c], pB, accO[0][nq], 0, 0, 0);
                accO[1][nq] = __builtin_amdgcn_mfma_f32_32x32x16_bf16(vfm[1][c], pB, accO[1][nq], 0, 0, 0);
                __builtin_amdgcn_s_setprio(0);
            }
        }
        __syncthreads();
    }

    // rowsum: lane holds k-halves with bit2==hf; partner is lane^32
    #pragma unroll
    for (int nq = 0; nq < 2; ++nq) accS[nq] += __shfl_xor(accS[nq], 32);
    const float inv0 = 1.f / accS[0], inv1 = 1.f / accS[1];

    // epilogue: normalize, transpose O^T->O via per-wave 8KB LDS region (reuses K/V bufs)
    u16* ep = smem + wave * 4096;   // 64 rows(q) x 64 cols(d), 16B-granule XOR swizzle
    #pragma unroll
    for (int nq = 0; nq < 2; ++nq) {
        const float inv = nq ? inv1 : inv0;
        const int row = nq * 32 + l31;
        #pragma unroll
        for (int dt = 0; dt < 2; ++dt)
            #pragma unroll
            for (int rq = 0; rq < 4; ++rq) {
                // accO reg r=rq*4+e -> d = dt*32 + rq*8 + 4*hf + e, q = row
                float v0 = accO[dt][nq][rq * 4 + 0] * inv;
                float v1 = accO[dt][nq][rq * 4 + 1] * inv;
                float v2 = accO[dt][nq][rq * 4 + 2] * inv;
                float v3 = accO[dt][nq][rq * 4 + 3] * inv;
                u32 dws[2] = { cvtpk(v0, v1), cvtpk(v2, v3) };
                const int g = dt * 4 + rq;
                __builtin_memcpy((char*)ep + row * 128 + ((g ^ l7) * 16) + hf * 8, dws, 8);
            }
    }
    // per-wave region: no cross-wave hazard; compiler orders ds write->read via lgkmcnt
    const int rl = lane >> 3, cl = lane & 7;
    #pragma unroll
    for (int pass = 0; pass < 8; ++pass) {
        const int row = pass * 8 + rl;
        bf16x8 vrow = ld16B((const u16*)((const char*)ep + row * 128 + ((cl ^ (row & 7)) * 16)));
        const int t = qt * 256 + wave * 64 + row;
        __builtin_memcpy(Y + ((size_t)(b * 2048 + t)) * 1024 + h * 64 + cl * 8, &vrow, 16);
    }
}

// ---------------- launch ----------------
extern "C" void kernel_launch(void* const* d_in, const int* in_sizes, int n_in,
                              void* d_out, int out_size, void* d_ws, size_t ws_size,
                              hipStream_t stream)
{
    const float* x  = (const float*)d_in[0];
    const float* Wq = (const float*)d_in[1];
    const float* bq = (const float*)d_in[2];
    const float* Wk = (const float*)d_in[3];
    const float* bk = (const float*)d_in[4];
    const float* Wv = (const float*)d_in[5];
    const float* bv = (const float*)d_in[6];
    const float* Wo = (const float*)d_in[7];
    const float* bo = (const float*)d_in[8];
    float* out = (float*)d_out;

    const size_t NTOK = (size_t)8192 * 1024;
    const size_t WN   = (size_t)1024 * 1024;
    u16* xb  = (u16*)d_ws;
    u16* wqb = xb + NTOK;     // wq, wk, wv contiguous => [3072,1024] fused weight
    u16* wkb = wqb + WN;
    u16* wvb = wkb + WN;
    u16* wob = wvb + WN;
    u16* q   = wob + WN;
    u16* k   = q + NTOK;
    u16* vt  = k + NTOK;
    u16* y   = vt + NTOK;

    convert_kernel<<<dim3(12288), 256, 0, stream>>>(x, Wq, Wk, Wv, Wo, xb, wqb, wkb, wvb, wob);
    qkv_kernel<<<dim3(1536), 256, 0, stream>>>(xb, wqb, bq, bk, bv, q, k, vt);
    attn_kernel<<<dim3(64, 8), 256, 0, stream>>>(q, k, vt, y);
    proj_kernel<<<dim3(512), 256, 0, stream>>>(y, wob, bo, out);
}